// Round 1
// baseline (14442.365 us; speedup 1.0000x reference)
//
#include <hip/hip_runtime.h>
#include <hip/hip_bf16.h>

// EncoderBiLSTMMaxPool — round 6: k_recur moved from VALU dot2 GEMV to persistent-weight MFMA.
// 8 WGs (chain q × dir d), 512 threads. Wave w owns units [32w,32w+32): 8 N-tiles of 16 gates
// ({i,f,g,o} × pair) -> activation is lane-local, ONE barrier/step (was 2 + plds exchange).
// Whh pre-swizzled to mfma_f32_16x16x32_f16 fragment order: 6 tiles/wave resident in 192 VGPRs,
// 2 tiles/wave streamed from LDS (128 KB, linear 16B/lane, conflict-free). h broadcast into all
// 16 A-rows (rows identical -> any D-row valid). Bias folded into xp at GEMM epilogue.

typedef _Float16 f16;
typedef _Float16 f16x8 __attribute__((ext_vector_type(8)));
typedef float    f32x4 __attribute__((ext_vector_type(4)));

#define B_  128
#define S_  128
#define H_  512
#define HH_ 256
#define M_  (B_ * S_)   // 16384
#define NG  1024        // gates per direction (4*HH)
#define K0  512         // LSTM input dim

__device__ __forceinline__ float sigmoidf_(float x) { return 1.0f / (1.0f + __expf(-x)); }
__device__ __forceinline__ float tanhf_(float x)    { return 1.0f - 2.0f / (__expf(2.0f * x) + 1.0f); }

__device__ __forceinline__ float ldf(const void* p, long i, int isbf) {
    return isbf ? __bfloat162float(((const __hip_bfloat16*)p)[i]) : ((const float*)p)[i];
}

// ---------------- dtype detection (bf16 vs fp32 input buffers) ----------------
__global__ void k_detect(const unsigned short* __restrict__ e, int* __restrict__ flag) {
    __shared__ int cnt;
    if (threadIdx.x == 0) cnt = 0;
    __syncthreads();
    unsigned short v = e[threadIdx.x];
    int ex = (v >> 7) & 0xFF;
    if (ex >= 100 && ex < 127) atomicAdd(&cnt, 1);
    __syncthreads();
    if (threadIdx.x == 0) *flag = (cnt >= 200) ? 1 : 0;   // 1 = bf16, 0 = fp32
}

// ---------------- embedding ----------------
__global__ void k_embed(const int* __restrict__ rt, const int* __restrict__ re, const int* __restrict__ rm,
                        const void* __restrict__ Ert, const void* __restrict__ Ere,
                        const void* __restrict__ Erm, f16* __restrict__ emb,
                        const int* __restrict__ flag) {
    const int isbf = *flag;
    int gid = blockIdx.x * 256 + threadIdx.x;      // < 16384*512
    int bs = gid >> 9, h = gid & 511;
    float v = ldf(Ert, (long)rt[bs] * H_ + h, isbf)
            + ldf(Ere, (long)re[bs] * H_ + h, isbf)
            + ldf(Erm, (long)rm[bs] * H_ + h, isbf);
    emb[gid] = (f16)v;
}

// ---------------- weight conversion ----------------
// wih: f16 rows for k_gemm (unchanged layout [2][2][1024][512]).
// whhF: MFMA fragment image [ld=4][gt=64][kf=8][lane=64][8] f16:
//   lane holds W[gate = gt*16 + (lane&15)][k = kf*32 + (lane>>4)*8 + j], j=0..7
//   (exact B-fragment layout used by the proven k_gemm below).
// bias: bih+bhh f32 [4][1024] — consumed by k_gemm epilogue (folded into xp).
__global__ void k_wconv(const void* __restrict__ Wih, const void* __restrict__ Whh,
                        const void* __restrict__ bih, const void* __restrict__ bhh,
                        f16* __restrict__ wih, f16* __restrict__ whhF, float* __restrict__ bias,
                        const int* __restrict__ flag) {
    const int isbf = *flag;
    int gid = blockIdx.x * 256 + threadIdx.x;      // < 2,097,152
    wih[gid] = (f16)ldf(Wih, gid, isbf);
    if (gid < 1048576) {
        int j  = gid & 7;
        int ln = (gid >> 3) & 63;
        int kf = (gid >> 9) & 7;
        int gt = (gid >> 12) & 63;
        int ld = gid >> 18;
        int gate = gt * 16 + (ln & 15);
        int k    = kf * 32 + (ln >> 4) * 8 + j;
        whhF[gid] = (f16)ldf(Whh, ((long)ld * 1024 + gate) * 256 + k, isbf);
    }
    if (gid < 4096) bias[gid] = ldf(bih, gid, isbf) + ldf(bhh, gid, isbf);
}

// ---------------- GEMM: C[16384][2048] = A[16384][512] * W[2048][512]^T + bias (f16, fp32 acc) ----------------
__global__ __launch_bounds__(256) void k_gemm(const f16* __restrict__ A, const f16* __restrict__ Bm,
                                              f16* __restrict__ C, const float* __restrict__ bias) {
    const int bm = blockIdx.x & 127;
    const int bn = blockIdx.x >> 7;
    const int tid = threadIdx.x;
    const int lane = tid & 63, wave = tid >> 6;
    const int wm = wave & 1, wn = wave >> 1;
    __shared__ __align__(16) f16 As[128][72];
    __shared__ __align__(16) f16 Bs[128][72];
    f32x4 acc[4][4];
#pragma unroll
    for (int i = 0; i < 4; ++i)
#pragma unroll
        for (int jj = 0; jj < 4; ++jj) acc[i][jj] = (f32x4){0.f, 0.f, 0.f, 0.f};
    const long abase = (long)bm * 128 * K0;
    const long bbase = (long)bn * 128 * K0;
    for (int kt = 0; kt < K0; kt += 64) {
#pragma unroll
        for (int p = 0; p < 4; ++p) {
            int r = p * 32 + (tid >> 3), s = tid & 7;
            *(int4*)&As[r][s * 8] = *(const int4*)(A  + abase + (long)r * K0 + kt + s * 8);
            *(int4*)&Bs[r][s * 8] = *(const int4*)(Bm + bbase + (long)r * K0 + kt + s * 8);
        }
        __syncthreads();
        const int quad = lane >> 4, l15 = lane & 15;
#pragma unroll
        for (int kc = 0; kc < 64; kc += 32) {
            f16x8 af[4], bf[4];
#pragma unroll
            for (int mt = 0; mt < 4; ++mt) af[mt] = *(const f16x8*)&As[wm * 64 + mt * 16 + l15][kc + quad * 8];
#pragma unroll
            for (int nt = 0; nt < 4; ++nt) bf[nt] = *(const f16x8*)&Bs[wn * 64 + nt * 16 + l15][kc + quad * 8];
#pragma unroll
            for (int mt = 0; mt < 4; ++mt)
#pragma unroll
                for (int nt = 0; nt < 4; ++nt)
                    acc[mt][nt] = __builtin_amdgcn_mfma_f32_16x16x32_f16(af[mt], bf[nt], acc[mt][nt], 0, 0, 0);
        }
        __syncthreads();
    }
    const int quad = lane >> 4, l15 = lane & 15;
#pragma unroll
    for (int mt = 0; mt < 4; ++mt)
#pragma unroll
        for (int nt = 0; nt < 4; ++nt) {
            int col = bn * 128 + wn * 64 + nt * 16 + l15;
            float bv = bias[col];
#pragma unroll
            for (int r = 0; r < 4; ++r) {
                int row = bm * 128 + wm * 64 + mt * 16 + quad * 4 + r;
                C[(long)row * 2048 + col] = (f16)(acc[mt][nt][r] + bv);
            }
        }
}

// ---------------- recurrence: persistent-weight MFMA GEMV ----------------
// 8 WGs = (chain q, dir d), 512 threads (8 waves), 1 WG/CU.
// Wave w owns units [32w, 32w+32): tiles gt = tt*16 + 2w + p (tt = gate type 0..3, p = pair 0..1).
// tt<3 resident in VGPRs (6 frags * 8 kf * 4 regs = 192), tt==3 streamed from LDS each step.
// h broadcast into all 16 MFMA A-rows -> every lane's acc[tt][p][r] equals gate (gt*16 + lane&15).
__global__ __launch_bounds__(512, 1) void k_recur(
    const f16* __restrict__ xp,     // [16384][2048] input projections (bias included)
    const f16* __restrict__ whhF,   // [4][64][8][64][8] f16 fragment image
    const void* __restrict__ h0, const void* __restrict__ c0,
    f16* __restrict__ yf16,         // layer0 out [16384][512]
    void* __restrict__ yout,        // layer1 out (d_out bilstm region)
    int layer, const int* __restrict__ flag) {
    const int isbf = *flag;
    const int q = blockIdx.x >> 1, d = blockIdx.x & 1;
    const int tid = threadIdx.x;
    const int w = tid >> 6, l = tid & 63;
    const int col = l & 15, quad = l >> 4;
    const int ld = layer * 2 + d;

    __shared__ __align__(16) f16 hbuf[2][256];
    __shared__ __align__(16) f16 wlds[8][2][8][64][8];   // [wave][pair][kf][lane][8] = 128 KB

    // ---- stage weights: 48 resident fragments + 16 LDS fragments per wave ----
    f16x8 wreg[3][2][8];
    {
        const f16* wb = whhF + (long)ld * (64 * 8 * 64 * 8);
#pragma unroll
        for (int tt = 0; tt < 4; ++tt)
#pragma unroll
            for (int p = 0; p < 2; ++p) {
                const int gt = tt * 16 + 2 * w + p;
#pragma unroll
                for (int kf = 0; kf < 8; ++kf) {
                    f16x8 fr = *(const f16x8*)(wb + (((long)gt * 8 + kf) * 64 + l) * 8);
                    if (tt < 3) wreg[tt][p][kf] = fr;
                    else        *(f16x8*)&wlds[w][p][kf][l][0] = fr;
                }
            }
    }

    // ---- init state: lane handles units u0 (pair 0) and u1 (pair 1); c replicated in all lanes ----
    const int u0 = 32 * w + col;
    const int u1 = u0 + 16;
    float cst0 = 0.f, cst1 = 0.f;
    if (q == 0) {                                   // chain 0 starts from h0/c0; others from reset
        cst0 = ldf(c0, ld * 256 + u0, isbf);
        cst1 = ldf(c0, ld * 256 + u1, isbf);
    }
    if (quad < 2) {
        int uu = quad ? u1 : u0;
        float hv = (q == 0) ? ldf(h0, ld * 256 + uu, isbf) : 0.f;
        hbuf[0][uu] = (f16)hv;
    }
    __syncthreads();                                // hbuf[0] + wlds ready

    // xp lane offset: gate(tt,p) = (tt*16+2w+p)*16+col -> d*1024 + tt*256 + p*16 + (32w+col)
    const int xlane = d * NG + 32 * w + col;

    // prefetch xp for step 0
    f16 px[4][2];
    {
        const f16* xr = xp + ((long)(q * 32) * 128 + (d ? 127 : 0)) * 2048 + xlane;
#pragma unroll
        for (int tt = 0; tt < 4; ++tt)
#pragma unroll
            for (int p = 0; p < 2; ++p) px[tt][p] = xr[tt * 256 + p * 16];
    }

    int cur = 0;
    for (int step = 0; step < 4096; ++step) {
        // acc init from prefetched xp (bias already folded in)
        f32x4 acc[4][2];
#pragma unroll
        for (int tt = 0; tt < 4; ++tt)
#pragma unroll
            for (int p = 0; p < 2; ++p) {
                float v = (float)px[tt][p];
                acc[tt][p] = (f32x4){v, v, v, v};
            }
        // issue next-step xp prefetch (lands during MFMA loop)
        {
            int s1 = (step < 4095) ? step + 1 : step;
            int b1 = q * 32 + (s1 >> 7), ti1 = s1 & 127;
            int t1 = d ? (127 - ti1) : ti1;
            const f16* xr1 = xp + ((long)b1 * 128 + t1) * 2048 + xlane;
#pragma unroll
            for (int tt = 0; tt < 4; ++tt)
#pragma unroll
                for (int p = 0; p < 2; ++p) px[tt][p] = xr1[tt * 256 + p * 16];
        }

        // MFMA: h (broadcast A) x Whh fragments, K=256 in 8 frags
        const f16* hb = hbuf[cur];
#pragma unroll
        for (int kf = 0; kf < 8; ++kf) {
            f16x8 ha = *(const f16x8*)&hb[kf * 32 + quad * 8];
#pragma unroll
            for (int tt = 0; tt < 3; ++tt)
#pragma unroll
                for (int p = 0; p < 2; ++p)
                    acc[tt][p] = __builtin_amdgcn_mfma_f32_16x16x32_f16(ha, wreg[tt][p][kf], acc[tt][p], 0, 0, 0);
#pragma unroll
            for (int p = 0; p < 2; ++p) {
                f16x8 wf = *(const f16x8*)&wlds[w][p][kf][l][0];
                acc[3][p] = __builtin_amdgcn_mfma_f32_16x16x32_f16(ha, wf, acc[3][p], 0, 0, 0);
            }
        }

        // activation (all lanes, redundant across quads -> no exchange needed)
        float ig0 = sigmoidf_(acc[0][0][0]);
        float fg0 = sigmoidf_(acc[1][0][0]);
        float gg0 = tanhf_(acc[2][0][0]);
        float og0 = sigmoidf_(acc[3][0][0]);
        cst0 = fg0 * cst0 + ig0 * gg0;
        float hn0 = og0 * tanhf_(cst0);

        float ig1 = sigmoidf_(acc[0][1][0]);
        float fg1 = sigmoidf_(acc[1][1][0]);
        float gg1 = tanhf_(acc[2][1][0]);
        float og1 = sigmoidf_(acc[3][1][0]);
        cst1 = fg1 * cst1 + ig1 * gg1;
        float hn1 = og1 * tanhf_(cst1);

        // write h (quads 0,1 are the designated writers) + sequence output
        {
            int b = q * 32 + (step >> 7), ti = step & 127;
            int t = d ? (127 - ti) : ti;
            if (quad < 2) {
                float hv = quad ? hn1 : hn0;
                int uu   = quad ? u1 : u0;
                hbuf[cur ^ 1][uu] = (f16)hv;
                long oidx = ((long)b * 128 + t) * 512 + d * 256 + uu;
                if (layer == 0) {
                    yf16[oidx] = (f16)hv;
                } else {
                    if (isbf) ((__hip_bfloat16*)yout)[oidx] = __float2bfloat16(hv);
                    else      ((float*)yout)[oidx] = hv;
                }
            }
        }
        cur ^= 1;
        __syncthreads();                            // hbuf[cur] ready for all waves
    }
}

// ---------------- max over batch axis ----------------
__global__ void k_maxpool(const void* __restrict__ bil, void* __restrict__ outbase,
                          const int* __restrict__ flag) {
    const int isbf = *flag;
    int gid = blockIdx.x * 256 + threadIdx.x;      // s*512+h, < 65536
    float m = -1e30f;
    for (int b = 0; b < 128; ++b)
        m = fmaxf(m, ldf(bil, (long)b * 65536 + gid, isbf));
    long o = (long)M_ * H_ + gid;
    if (isbf) ((__hip_bfloat16*)outbase)[o] = __float2bfloat16(m);
    else      ((float*)outbase)[o] = m;
}

extern "C" void kernel_launch(void* const* d_in, const int* in_sizes, int n_in,
                              void* d_out, int out_size, void* d_ws, size_t ws_size,
                              hipStream_t stream) {
    const int* rt = (const int*)d_in[0];
    const int* re = (const int*)d_in[1];
    const int* rm = (const int*)d_in[2];
    const void* h0  = d_in[3];
    const void* c0  = d_in[4];
    const void* Ert = d_in[5];
    const void* Ere = d_in[6];
    const void* Erm = d_in[7];
    const void* Wih = d_in[8];
    const void* Whh = d_in[9];
    const void* bih = d_in[10];
    const void* bhh = d_in[11];

    if (ws_size < 106971200u) return;

    char* ws = (char*)d_ws;
    f16*   emb  = (f16*)(ws);                      // 16,777,216 B
    f16*   wih  = (f16*)(ws + 16777216);           //  4,194,304 B  [2][2][1024][512]
    f16*   whhF = (f16*)(ws + 20971520);           //  2,097,152 B  [4][64][8][64][8] fragment image
    float* bias = (float*)(ws + 23068672);         //     16,384 B  [2][2][1024]
    f16*   xpb  = (f16*)(ws + 23085056);           // 67,108,864 B  [16384][2048]
    f16*   y0   = (f16*)(ws + 90193920);           // 16,777,216 B  [16384][512]
    int*   flag = (int*)(ws + 106971136);          //          4 B

    hipLaunchKernelGGL(k_detect, dim3(1),     dim3(256), 0, stream, (const unsigned short*)Ert, flag);
    hipLaunchKernelGGL(k_embed,  dim3(32768), dim3(256), 0, stream, rt, re, rm, Ert, Ere, Erm, emb, flag);
    hipLaunchKernelGGL(k_wconv,  dim3(8192),  dim3(256), 0, stream, Wih, Whh, bih, bhh, wih, whhF, bias, flag);
    hipLaunchKernelGGL(k_gemm,   dim3(2048),  dim3(256), 0, stream, emb, wih, xpb, bias);
    hipLaunchKernelGGL(k_recur,  dim3(8),     dim3(512), 0, stream, xpb, whhF, h0, c0, y0, d_out, 0, flag);
    hipLaunchKernelGGL(k_gemm,   dim3(2048),  dim3(256), 0, stream, y0, wih + (long)2 * NG * K0, xpb, bias + 2048);
    hipLaunchKernelGGL(k_recur,  dim3(8),     dim3(512), 0, stream, xpb, whhF, h0, c0, y0, d_out, 1, flag);
    hipLaunchKernelGGL(k_maxpool,dim3(256),   dim3(256), 0, stream, d_out, d_out, flag);
}